// Round 8
// baseline (9752.421 us; speedup 1.0000x reference)
//
#include <hip/hip_runtime.h>

// LSTM forward, B=32 T=1024 D=512 U=512, fp32.
// Persistent fused kernel, 256 WGs x 512 thr (all co-resident, grid == #CUs).
// Group g = blockIdx&7 handles batches 4g..4g+3; WG w = blockIdx>>3 owns
// 16 units. Weights in VGPRs (128 floats/thread).
//
// R8: wave-autonomous critical path. Crit wave wv (of waves 0-3) owns units
// [4wv,4wv+4) with ALL 4 gates and FULL k=512:
//   poll h(t-1) (8x dwordx4 data-poll, sentinel, LLC scope, 1 RTT)
//   -> stage ALL 2048 words to shared LH (all waves write identical values;
//      benign race -- a wave passes detect(t) only after every same-WG wave
//      stored h(t), hence finished reading LH(t-1))
//   -> dot (2 cols x 64k per lane) -> shfl_xor k-reduce (8,16,32)
//   -> per-wave LDS bounce to (b,col) lanes -> shfl_xor(4,8) gate gather
//   -> gates in-wave (4x redundant, deterministic) -> 16 lanes store h.
// NO cross-wave barrier, NO LR buffer, NO wave0 serialization.
// xz pipeline (waves 4-7): unchanged free-running ring producer.

#define TT 1024
#define DD 512
#define UU 512
#define NCOL 2048
#define SENT 0xFFFFFFFFu
#define RDEPTH 4

typedef unsigned int u32x4 __attribute__((ext_vector_type(4)));

__device__ __forceinline__ float hsig(float v) {
  return fminf(fmaxf(0.2f * v + 0.5f, 0.0f), 1.0f);
}
__device__ __forceinline__ float tanh_fast(float x) {
  float e = __expf(2.0f * x);
  return 1.0f - 2.0f / (e + 1.0f);
}

// xz-side 64-k dot (unchanged from R5-R7).
__device__ __forceinline__ void dot64x2_4(
    const float* p0, const float* p1, const float* p2, const float* p3,
    const float (&W)[128],
    float& a00, float& a01, float& a10, float& a11,
    float& a20, float& a21, float& a30, float& a31) {
  a00 = a01 = a10 = a11 = a20 = a21 = a30 = a31 = 0.f;
#pragma unroll
  for (int j4 = 0; j4 < 16; ++j4) {
    float4 v0 = *(const float4*)(p0 + j4 * 4);
    float4 v1 = *(const float4*)(p1 + j4 * 4);
    float4 v2 = *(const float4*)(p2 + j4 * 4);
    float4 v3 = *(const float4*)(p3 + j4 * 4);
    const float* e0 = (const float*)&v0;
    const float* e1 = (const float*)&v1;
    const float* e2 = (const float*)&v2;
    const float* e3 = (const float*)&v3;
#pragma unroll
    for (int jj = 0; jj < 4; ++jj) {
      float w0 = W[2 * (4 * j4 + jj) + 0];
      float w1 = W[2 * (4 * j4 + jj) + 1];
      a00 += e0[jj] * w0; a01 += e0[jj] * w1;
      a10 += e1[jj] * w0; a11 += e1[jj] * w1;
      a20 += e2[jj] * w0; a21 += e2[jj] * w1;
      a30 += e3[jj] * w0; a31 += e3[jj] * w1;
    }
  }
}

template <bool SLEEP>
__device__ __forceinline__ void wavebar(int* ctr, int& ep) {
  asm volatile("s_waitcnt lgkmcnt(0)" ::: "memory");
  if ((threadIdx.x & 63) == 0)
    __hip_atomic_fetch_add(ctr, 1, __ATOMIC_RELAXED, __HIP_MEMORY_SCOPE_WORKGROUP);
  ep += 4;
  while (__hip_atomic_load(ctr, __ATOMIC_RELAXED, __HIP_MEMORY_SCOPE_WORKGROUP) < ep) {
    if (SLEEP) __builtin_amdgcn_s_sleep(1);
  }
  asm volatile("" ::: "memory");
}

__global__ __launch_bounds__(512, 2) void lstm_persistent(
    const float* __restrict__ x,
    const float* __restrict__ Wk,
    const float* __restrict__ Wr,
    const float* __restrict__ bias,
    float* __restrict__ out) {
  const int tid = (int)threadIdx.x;
  const int g   = (int)blockIdx.x & 7;
  const int w   = (int)blockIdx.x >> 3;
  const bool crit = (tid < 256);
  const int l   = tid & 63;

  __shared__ float LX[8][4][65];        // xz partials
  __shared__ float RING[RDEPTH][4][66]; // reduced xz ring
  __shared__ float LH[4][8][68];        // h(t-1): [batch][kq][64+pad]
  __shared__ float ZB[4][4][18];        // per-wave z bounce [wv][b][16+pad]
  __shared__ float LB[64];              // bias slice (WG-col space)
  __shared__ int cXZdone, cCRITdone, cXZbar;

  if (tid == 0) { cXZdone = 0; cCRITdone = 0; cXZbar = 0; }
  if (tid < 64) LB[tid] = bias[(tid >> 4) * UU + w * 16 + (tid & 15)];

  // ---- weight slices in VGPRs ----
  float W[128];
  if (crit) {
    const int wv = tid >> 6;        // crit wave 0..3
    const int kq = l >> 3;          // k-range [64kq, 64kq+64)
    const int cp = l & 7;           // col-pair (local cols 2cp, 2cp+1)
    const int gate = cp >> 1;
    const int uu2  = (2 * cp) & 3;  // 0 or 2; cols adjacent in gcol space
    const int gcb  = gate * UU + w * 16 + 4 * wv + uu2;
#pragma unroll
    for (int j = 0; j < 64; ++j) {
      float2 ww = *(const float2*)(Wr + (size_t)(64 * kq + j) * NCOL + gcb);
      W[2 * j] = ww.x; W[2 * j + 1] = ww.y;
    }
  } else {
    const int idx = tid & 255;
    const int o   = idx >> 5;
    const int col0 = (idx & 31) * 2;
    const int gcolX = ((col0 >> 4) * UU) + w * 16 + (col0 & 15);
#pragma unroll
    for (int j = 0; j < 64; ++j) {
      float2 ww = *(const float2*)(Wk + (size_t)(o * 64 + j) * NCOL + gcolX);
      W[2 * j] = ww.x; W[2 * j + 1] = ww.y;
    }
  }
  __syncthreads();  // one-time init barrier only

  if (crit) {
    // ---------------- critical path: waves 0-3, fully wave-autonomous ----
    const int wv  = tid >> 6;
    const int kq  = l >> 3;
    const int cp  = l & 7;
    const int b16 = l >> 4;      // z-distribution: batch
    const int col_l = l & 15;    // z-distribution: local col (gate*4+uu)
    const int gsel = col_l >> 2; // gate index of this lane
    const int cc = (col_l >> 2) * 16 + 4 * wv + (col_l & 3);  // WG-col space
    // Poll layout: lane covers batch b_p, units u16p*4 + {0..3} + 64s + 128blk.
    const int b_p  = l >> 4;
    const int u16p = l & 15;
    const unsigned* hb = (const unsigned*)out +
        (size_t)(g * 4 + b_p) * TT * UU + u16p * 4;  // row 0 (= h(t=0)) base
    float c_state = 0.0f;

    for (int t = 0; t < TT; ++t) {
      float zrec = 0.0f;
      if (t > 0) {
        // ---- data-poll all 2048 words of h(t-1): 8 dwordx4, 1 RTT ----
        u32x4 d0, d1, d2, d3, d4, d5, d6, d7;
        for (;;) {
          asm volatile(
              "global_load_dwordx4 %0, %8, off sc0 sc1\n\t"
              "global_load_dwordx4 %1, %8, off offset:256 sc0 sc1\n\t"
              "global_load_dwordx4 %2, %8, off offset:512 sc0 sc1\n\t"
              "global_load_dwordx4 %3, %8, off offset:768 sc0 sc1\n\t"
              "global_load_dwordx4 %4, %8, off offset:1024 sc0 sc1\n\t"
              "global_load_dwordx4 %5, %8, off offset:1280 sc0 sc1\n\t"
              "global_load_dwordx4 %6, %8, off offset:1536 sc0 sc1\n\t"
              "global_load_dwordx4 %7, %8, off offset:1792 sc0 sc1\n\t"
              "s_waitcnt vmcnt(0)"
              : "=v"(d0), "=v"(d1), "=v"(d2), "=v"(d3),
                "=v"(d4), "=v"(d5), "=v"(d6), "=v"(d7)
              : "v"(hb)
              : "memory");
          int ok = (d0.x != SENT) & (d0.y != SENT) & (d0.z != SENT) & (d0.w != SENT);
          ok &= (d1.x != SENT) & (d1.y != SENT) & (d1.z != SENT) & (d1.w != SENT);
          ok &= (d2.x != SENT) & (d2.y != SENT) & (d2.z != SENT) & (d2.w != SENT);
          ok &= (d3.x != SENT) & (d3.y != SENT) & (d3.z != SENT) & (d3.w != SENT);
          ok &= (d4.x != SENT) & (d4.y != SENT) & (d4.z != SENT) & (d4.w != SENT);
          ok &= (d5.x != SENT) & (d5.y != SENT) & (d5.z != SENT) & (d5.w != SENT);
          ok &= (d6.x != SENT) & (d6.y != SENT) & (d6.z != SENT) & (d6.w != SENT);
          ok &= (d7.x != SENT) & (d7.y != SENT) & (d7.z != SENT) & (d7.w != SENT);
          if (__all(ok)) break;
          __builtin_amdgcn_s_sleep(2);
        }
        hb += UU;  // next step polls the next h row
        // ---- stage to shared LH (all waves write identical values) ----
        *(u32x4*)&LH[b_p][0][u16p * 4] = d0;
        *(u32x4*)&LH[b_p][1][u16p * 4] = d1;
        *(u32x4*)&LH[b_p][2][u16p * 4] = d2;
        *(u32x4*)&LH[b_p][3][u16p * 4] = d3;
        *(u32x4*)&LH[b_p][4][u16p * 4] = d4;
        *(u32x4*)&LH[b_p][5][u16p * 4] = d5;
        *(u32x4*)&LH[b_p][6][u16p * 4] = d6;
        *(u32x4*)&LH[b_p][7][u16p * 4] = d7;
        asm volatile("s_waitcnt lgkmcnt(0)" ::: "memory");
        __builtin_amdgcn_sched_barrier(0);
        // ---- dot: 2 cols x 64 k x 4 batches per lane ----
        __builtin_amdgcn_s_setprio(1);
        float acc[4][2];
#pragma unroll
        for (int b = 0; b < 4; ++b) { acc[b][0] = 0.f; acc[b][1] = 0.f; }
#pragma unroll
        for (int b = 0; b < 4; ++b) {
#pragma unroll
          for (int j4 = 0; j4 < 16; ++j4) {
            float4 v = *(const float4*)&LH[b][kq][4 * j4];
            const float* e = (const float*)&v;
#pragma unroll
            for (int jj = 0; jj < 4; ++jj) {
              acc[b][0] += e[jj] * W[8 * j4 + 2 * jj + 0];
              acc[b][1] += e[jj] * W[8 * j4 + 2 * jj + 1];
            }
          }
        }
        __builtin_amdgcn_s_setprio(0);
        // ---- k-reduce across the 8 kq lane-groups (xor butterfly) ----
#pragma unroll
        for (int b = 0; b < 4; ++b) {
          acc[b][0] += __shfl_xor(acc[b][0], 8);
          acc[b][1] += __shfl_xor(acc[b][1], 8);
          acc[b][0] += __shfl_xor(acc[b][0], 16);
          acc[b][1] += __shfl_xor(acc[b][1], 16);
          acc[b][0] += __shfl_xor(acc[b][0], 32);
          acc[b][1] += __shfl_xor(acc[b][1], 32);
        }
        // ---- bounce to (b,col) lane layout via per-wave LDS ----
        if (l < 8) {  // kq==0 lanes: cp == l
#pragma unroll
          for (int b = 0; b < 4; ++b)
            *(float2*)&ZB[wv][b][2 * l] = make_float2(acc[b][0], acc[b][1]);
        }
        asm volatile("s_waitcnt lgkmcnt(0)" ::: "memory");
        zrec = ZB[wv][b16][col_l];
      }
      // ---- xz ring (per-wave wait; xz normally runs ahead) ----
      while (__hip_atomic_load(&cXZdone, __ATOMIC_RELAXED,
                               __HIP_MEMORY_SCOPE_WORKGROUP) < t + 1) {
      }
      asm volatile("" ::: "memory");
      float zfull = zrec + RING[t & (RDEPTH - 1)][b16][cc] + LB[cc];
      if (l == 0)
        __hip_atomic_fetch_add(&cCRITdone, 1, __ATOMIC_RELAXED,
                               __HIP_MEMORY_SCOPE_WORKGROUP);
      // ---- gate gather: lanes b*16 + gate*4 + uu; xor 4 -> gate^1, 8 -> gate^2
      float za  = __shfl_xor(zfull, 4);
      float zb  = __shfl_xor(zfull, 8);
      float zc2 = __shfl_xor(za, 8);
      float zi  = gsel == 0 ? zfull : gsel == 1 ? za    : gsel == 2 ? zb    : zc2;
      float zf  = gsel == 0 ? za    : gsel == 1 ? zfull : gsel == 2 ? zc2   : zb;
      float zc_ = gsel == 0 ? zb    : gsel == 1 ? zc2   : gsel == 2 ? zfull : za;
      float zo  = gsel == 0 ? zc2   : gsel == 1 ? zb    : gsel == 2 ? za    : zfull;
      float gi = hsig(zi);
      float gf = hsig(zf);
      float gc = tanh_fast(zc_);
      float go = hsig(zo);
      c_state = gf * c_state + gi * gc;  // 4x redundant, identical ops
      float h = go * tanh_fast(c_state);
      if (gsel == 0) {  // 16 lanes: (b16, unit 4wv + col_l)
        __hip_atomic_store(
            out + ((size_t)(g * 4 + b16) * TT + t) * UU + w * 16 + 4 * wv + col_l,
            h, __ATOMIC_RELAXED, __HIP_MEMORY_SCOPE_AGENT);
      }
    }
  } else {
    // ---------------- xz pipeline: waves 4-7 (free-running) ----------------
    const int idx = tid & 255;
    const int o   = idx >> 5;
    const int col0 = (idx & 31) * 2;
    const float* xb0 = x + (size_t)(g * 4 + 0) * TT * DD + o * 64;
    const float* xb1 = x + (size_t)(g * 4 + 1) * TT * DD + o * 64;
    const float* xb2 = x + (size_t)(g * 4 + 2) * TT * DD + o * 64;
    const float* xb3 = x + (size_t)(g * 4 + 3) * TT * DD + o * 64;
    int epX = 0;

    for (int t = 0; t < TT; ++t) {
      size_t off = (size_t)t * DD;
      float a00, a01, a10, a11, a20, a21, a30, a31;
      dot64x2_4(xb0 + off, xb1 + off, xb2 + off, xb3 + off, W,
                a00, a01, a10, a11, a20, a21, a30, a31);
      *(float2*)&LX[o][0][col0] = make_float2(a00, a01);
      *(float2*)&LX[o][1][col0] = make_float2(a10, a11);
      *(float2*)&LX[o][2][col0] = make_float2(a20, a21);
      *(float2*)&LX[o][3][col0] = make_float2(a30, a31);
      wavebar<true>(&cXZbar, epX);  // partials visible
      // ring slot t&3 free? (all 4 crit waves consumed slot t-RDEPTH)
      if (t >= RDEPTH) {
        while (__hip_atomic_load(&cCRITdone, __ATOMIC_RELAXED,
                                 __HIP_MEMORY_SCOPE_WORKGROUP) <
               4 * (t - RDEPTH + 1)) {
          __builtin_amdgcn_s_sleep(1);
        }
        asm volatile("" ::: "memory");
      }
      {
        const int b2 = idx >> 6, c3 = idx & 63;
        float ssum = 0.f;
#pragma unroll
        for (int oo = 0; oo < 8; ++oo) ssum += LX[oo][b2][c3];
        RING[t & (RDEPTH - 1)][b2][c3] = ssum;
      }
      wavebar<true>(&cXZbar, epX);  // reduce complete (guards LX overwrite)
      if (idx == 0) {
        asm volatile("s_waitcnt lgkmcnt(0)" ::: "memory");
        __hip_atomic_fetch_add(&cXZdone, 1, __ATOMIC_RELAXED,
                               __HIP_MEMORY_SCOPE_WORKGROUP);
      }
    }
  }
}

extern "C" void kernel_launch(void* const* d_in, const int* in_sizes, int n_in,
                              void* d_out, int out_size, void* d_ws, size_t ws_size,
                              hipStream_t stream) {
  const float* x    = (const float*)d_in[0];
  const float* Wk   = (const float*)d_in[1];
  const float* Wr   = (const float*)d_in[2];
  const float* bias = (const float*)d_in[3];
  float* out = (float*)d_out;

  // Sentinel-fill the h history (graph-capturable async memset).
  hipMemsetAsync(out, 0xFF, (size_t)out_size * sizeof(float), stream);
  lstm_persistent<<<256, 512, 0, stream>>>(x, Wk, Wr, bias, out);
}

// Round 9
// 4273.860 us; speedup vs baseline: 2.2819x; 2.2819x over previous
//
#include <hip/hip_runtime.h>

// LSTM forward, B=32 T=1024 D=512 U=512, fp32.
// Persistent fused kernel, 256 WGs x 512 thr (all co-resident, grid == #CUs).
// Group g = blockIdx&7 handles batches 4g..4g+3; WG w = blockIdx>>3 owns
// 16 units (64 gate cols). Weights in VGPRs as f32x2 col-pairs.
//
// R9 = R6's proven slice-local sentinel data-poll (RELAXED+AGENT, 1 RTT,
// 8 producers per wave) + distributed tail + packed FMA:
//  - crit wave wv polls units [128wv,128wv+128) x 4 batches of h(t-1),
//    stages to its private LH octants, dots immediately (f32x2 acc,
//    v_pk_fma), writes LR partials (parity-buffered), B2,
//    then computes gates for BATCH wv only (16 lanes, own c_state,
//    own h store) -- no wave0 funnel.
//  - LR[t&1] parity: dot(t+1) writes other parity than gates(t) reads;
//    B2(t+1) orders the next reuse. Race-free with ONE barrier per step.
//  - xz waves 4-7: free-running ring producer (R5 structure), f32x2 dot.

#define TT 1024
#define DD 512
#define UU 512
#define NCOL 2048
#define SENT 0xFFFFFFFFu
#define RDEPTH 4

typedef float f32x2 __attribute__((ext_vector_type(2)));
typedef float f32x4 __attribute__((ext_vector_type(4)));

__device__ __forceinline__ float hsig(float v) {
  return fminf(fmaxf(0.2f * v + 0.5f, 0.0f), 1.0f);
}
__device__ __forceinline__ float tanh_fast(float x) {
  float e = __expf(2.0f * x);
  return 1.0f - 2.0f / (e + 1.0f);
}

// Epoch barrier for the 4 waves of one half (waves 0-3 or 4-7).
template <bool SLEEP>
__device__ __forceinline__ void wavebar(int* ctr, int& ep) {
  asm volatile("s_waitcnt lgkmcnt(0)" ::: "memory");
  if ((threadIdx.x & 63) == 0)
    __hip_atomic_fetch_add(ctr, 1, __ATOMIC_RELAXED, __HIP_MEMORY_SCOPE_WORKGROUP);
  ep += 4;
  while (__hip_atomic_load(ctr, __ATOMIC_RELAXED, __HIP_MEMORY_SCOPE_WORKGROUP) < ep) {
    if (SLEEP) __builtin_amdgcn_s_sleep(1);
  }
  asm volatile("" ::: "memory");
}

__global__ __launch_bounds__(512, 2) void lstm_persistent(
    const float* __restrict__ x,
    const float* __restrict__ Wk,
    const float* __restrict__ Wr,
    const float* __restrict__ bias,
    float* __restrict__ out) {
  const int tid = (int)threadIdx.x;
  const int g   = (int)blockIdx.x & 7;
  const int w   = (int)blockIdx.x >> 3;
  const bool crit = (tid < 256);
  const int l   = tid & 63;

  __shared__ float LX[8][4][65];         // xz partials
  __shared__ float LR[2][8][4][66];      // recurrent partials, parity by t
  __shared__ float RING[RDEPTH][4][66];  // reduced xz ring
  __shared__ float LH[4][8][68];         // h(t-1): [batch][k-octant][64] pad->16B-aligned, 4-bank skew
  __shared__ float LB[64];               // bias slice (WG-col space)
  __shared__ int cXZdone, cCRITdone, cXZbar, cCRITbar;

  if (tid == 0) { cXZdone = 0; cCRITdone = 0; cXZbar = 0; cCRITbar = 0; }
  if (tid < 64) LB[tid] = bias[(tid >> 4) * UU + w * 16 + (tid & 15)];

  // ---- weight slices in VGPRs (f32x2 col-pairs) ----
  // crit wave wv: k-octant kql = 2wv + (l>>5), col-pair cp = l&31.
  // xz wave: k-octant o = idx>>5, col-pair cp = idx&31.
  f32x2 W2[64];
  {
    const int wv  = tid >> 6;
    const int idx = tid & 255;
    const int cp  = crit ? (l & 31) : (idx & 31);
    const int ko  = crit ? (2 * (wv & 3) + (l >> 5)) : (idx >> 5);
    const int gcb = (cp >> 3) * UU + w * 16 + ((2 * cp) & 15);
    const float* M = crit ? Wr : Wk;
#pragma unroll
    for (int j = 0; j < 64; ++j)
      W2[j] = *(const f32x2*)(M + (size_t)(64 * ko + j) * NCOL + gcb);
  }
  __syncthreads();  // one-time init barrier only

  if (crit) {
    // ---------------- critical path: waves 0-3 ----------------
    const int wv  = tid >> 6;        // wave id; owns poll-slice + batch wv
    const int kq0 = 2 * wv;          // staged octants kq0, kq0+1
    const int kql = kq0 + (l >> 5);  // this lane's dot octant
    const int cp  = l & 31;          // col-pair (cols 2cp, 2cp+1)
    const unsigned* ou0 = (const unsigned*)out + (size_t)(g * 4 + 0) * TT * UU;
    const unsigned* ou1 = (const unsigned*)out + (size_t)(g * 4 + 1) * TT * UU;
    const unsigned* ou2 = (const unsigned*)out + (size_t)(g * 4 + 2) * TT * UU;
    const unsigned* ou3 = (const unsigned*)out + (size_t)(g * 4 + 3) * TT * UU;
    float c_state = 0.0f;            // lanes 0-15: c for (batch wv, unit l)
    int epC = 0;

    for (int t = 0; t < TT; ++t) {
      if (t > 0) {
        // ---- slice-local data-poll: 8 words, 1 RTT, 8 producer WGs ----
        const size_t roff = (size_t)(t - 1) * UU + 128 * wv + l;
        unsigned v0, v1, v2, v3, v4, v5, v6, v7;
        for (;;) {
          v0 = __hip_atomic_load(ou0 + roff,      __ATOMIC_RELAXED, __HIP_MEMORY_SCOPE_AGENT);
          v1 = __hip_atomic_load(ou0 + roff + 64, __ATOMIC_RELAXED, __HIP_MEMORY_SCOPE_AGENT);
          v2 = __hip_atomic_load(ou1 + roff,      __ATOMIC_RELAXED, __HIP_MEMORY_SCOPE_AGENT);
          v3 = __hip_atomic_load(ou1 + roff + 64, __ATOMIC_RELAXED, __HIP_MEMORY_SCOPE_AGENT);
          v4 = __hip_atomic_load(ou2 + roff,      __ATOMIC_RELAXED, __HIP_MEMORY_SCOPE_AGENT);
          v5 = __hip_atomic_load(ou2 + roff + 64, __ATOMIC_RELAXED, __HIP_MEMORY_SCOPE_AGENT);
          v6 = __hip_atomic_load(ou3 + roff,      __ATOMIC_RELAXED, __HIP_MEMORY_SCOPE_AGENT);
          v7 = __hip_atomic_load(ou3 + roff + 64, __ATOMIC_RELAXED, __HIP_MEMORY_SCOPE_AGENT);
          int ok = (v0 != SENT) & (v1 != SENT) & (v2 != SENT) & (v3 != SENT) &
                   (v4 != SENT) & (v5 != SENT) & (v6 != SENT) & (v7 != SENT);
          if (__all(ok)) break;
          __builtin_amdgcn_s_sleep(1);
        }
        // ---- stage into this wave's private LH octants ----
        LH[0][kq0    ][l] = __uint_as_float(v0);
        LH[0][kq0 + 1][l] = __uint_as_float(v1);
        LH[1][kq0    ][l] = __uint_as_float(v2);
        LH[1][kq0 + 1][l] = __uint_as_float(v3);
        LH[2][kq0    ][l] = __uint_as_float(v4);
        LH[2][kq0 + 1][l] = __uint_as_float(v5);
        LH[3][kq0    ][l] = __uint_as_float(v6);
        LH[3][kq0 + 1][l] = __uint_as_float(v7);
        asm volatile("s_waitcnt lgkmcnt(0)" ::: "memory");
        __builtin_amdgcn_sched_barrier(0);
        // ---- dot: 2 cols x 64 k x 4 batches, f32x2 acc (v_pk_fma) ----
        __builtin_amdgcn_s_setprio(1);
        f32x2 a0 = {0.f, 0.f}, a1 = {0.f, 0.f}, a2 = {0.f, 0.f}, a3 = {0.f, 0.f};
#pragma unroll
        for (int j4 = 0; j4 < 16; ++j4) {
          f32x4 h0 = *(const f32x4*)&LH[0][kql][4 * j4];
          f32x4 h1 = *(const f32x4*)&LH[1][kql][4 * j4];
          f32x4 h2 = *(const f32x4*)&LH[2][kql][4 * j4];
          f32x4 h3 = *(const f32x4*)&LH[3][kql][4 * j4];
#pragma unroll
          for (int jj = 0; jj < 4; ++jj) {
            f32x2 wj = W2[4 * j4 + jj];
            a0 += (f32x2){h0[jj], h0[jj]} * wj;
            a1 += (f32x2){h1[jj], h1[jj]} * wj;
            a2 += (f32x2){h2[jj], h2[jj]} * wj;
            a3 += (f32x2){h3[jj], h3[jj]} * wj;
          }
        }
        __builtin_amdgcn_s_setprio(0);
        const int p = t & 1;
        *(f32x2*)&LR[p][kql][0][2 * cp] = a0;
        *(f32x2*)&LR[p][kql][1][2 * cp] = a1;
        *(f32x2*)&LR[p][kql][2][2 * cp] = a2;
        *(f32x2*)&LR[p][kql][3][2 * cp] = a3;
      }
      // ---- pre-gate: xz + bias for batch wv (lanes 0-15), before B2 ----
      float s0 = 0.f, s1 = 0.f, s2 = 0.f, s3 = 0.f;
      if (l < 16) {
        while (__hip_atomic_load(&cXZdone, __ATOMIC_RELAXED,
                                 __HIP_MEMORY_SCOPE_WORKGROUP) < t + 1) {
        }
        asm volatile("" ::: "memory");
        const int ss = t & (RDEPTH - 1);
        s0 = RING[ss][wv][l +  0] + LB[l +  0];
        s1 = RING[ss][wv][l + 16] + LB[l + 16];
        s2 = RING[ss][wv][l + 32] + LB[l + 32];
        s3 = RING[ss][wv][l + 48] + LB[l + 48];
      }
      wavebar<false>(&cCRITbar, epC);  // B2: all LR partials complete
      if (l == 0)
        __hip_atomic_fetch_add(&cCRITdone, 1, __ATOMIC_RELAXED,
                               __HIP_MEMORY_SCOPE_WORKGROUP);
      // ---- gates for batch wv, units w*16 + l (lanes 0-15) ----
      if (l < 16) {
        if (t > 0) {
          const int p = t & 1;
#pragma unroll
          for (int kq = 0; kq < 8; ++kq) {
            s0 += LR[p][kq][wv][l +  0];
            s1 += LR[p][kq][wv][l + 16];
            s2 += LR[p][kq][wv][l + 32];
            s3 += LR[p][kq][wv][l + 48];
          }
        }
        float gi = hsig(s0);
        float gf = hsig(s1);
        float gc = tanh_fast(s2);
        float go = hsig(s3);
        c_state = gf * c_state + gi * gc;
        float h = go * tanh_fast(c_state);
        __hip_atomic_store(
            out + ((size_t)(g * 4 + wv) * TT + t) * UU + w * 16 + l, h,
            __ATOMIC_RELAXED, __HIP_MEMORY_SCOPE_AGENT);
      }
    }
  } else {
    // ---------------- xz pipeline: waves 4-7 (free-running) ----------------
    const int idx = tid & 255;
    const int o   = idx >> 5;
    const int cp  = idx & 31;
    const float* xb0 = x + (size_t)(g * 4 + 0) * TT * DD + o * 64;
    const float* xb1 = x + (size_t)(g * 4 + 1) * TT * DD + o * 64;
    const float* xb2 = x + (size_t)(g * 4 + 2) * TT * DD + o * 64;
    const float* xb3 = x + (size_t)(g * 4 + 3) * TT * DD + o * 64;
    int epX = 0;

    for (int t = 0; t < TT; ++t) {
      const size_t off = (size_t)t * DD;
      f32x2 a0 = {0.f, 0.f}, a1 = {0.f, 0.f}, a2 = {0.f, 0.f}, a3 = {0.f, 0.f};
#pragma unroll
      for (int j4 = 0; j4 < 16; ++j4) {
        f32x4 v0 = *(const f32x4*)(xb0 + off + 4 * j4);
        f32x4 v1 = *(const f32x4*)(xb1 + off + 4 * j4);
        f32x4 v2 = *(const f32x4*)(xb2 + off + 4 * j4);
        f32x4 v3 = *(const f32x4*)(xb3 + off + 4 * j4);
#pragma unroll
        for (int jj = 0; jj < 4; ++jj) {
          f32x2 wj = W2[4 * j4 + jj];
          a0 += (f32x2){v0[jj], v0[jj]} * wj;
          a1 += (f32x2){v1[jj], v1[jj]} * wj;
          a2 += (f32x2){v2[jj], v2[jj]} * wj;
          a3 += (f32x2){v3[jj], v3[jj]} * wj;
        }
      }
      *(f32x2*)&LX[o][0][2 * cp] = a0;
      *(f32x2*)&LX[o][1][2 * cp] = a1;
      *(f32x2*)&LX[o][2][2 * cp] = a2;
      *(f32x2*)&LX[o][3][2 * cp] = a3;
      wavebar<true>(&cXZbar, epX);  // partials visible
      // ring slot t&3 free? (all 4 crit waves consumed slot t-RDEPTH)
      if (t >= RDEPTH) {
        while (__hip_atomic_load(&cCRITdone, __ATOMIC_RELAXED,
                                 __HIP_MEMORY_SCOPE_WORKGROUP) <
               4 * (t - RDEPTH + 1)) {
          __builtin_amdgcn_s_sleep(1);
        }
        asm volatile("" ::: "memory");
      }
      {
        const int b2 = idx >> 6, c3 = idx & 63;
        float ssum = 0.f;
#pragma unroll
        for (int oo = 0; oo < 8; ++oo) ssum += LX[oo][b2][c3];
        RING[t & (RDEPTH - 1)][b2][c3] = ssum;
      }
      wavebar<true>(&cXZbar, epX);  // reduce complete (guards LX overwrite)
      if (idx == 0) {
        asm volatile("s_waitcnt lgkmcnt(0)" ::: "memory");
        __hip_atomic_fetch_add(&cXZdone, 1, __ATOMIC_RELAXED,
                               __HIP_MEMORY_SCOPE_WORKGROUP);
      }
    }
  }
}

extern "C" void kernel_launch(void* const* d_in, const int* in_sizes, int n_in,
                              void* d_out, int out_size, void* d_ws, size_t ws_size,
                              hipStream_t stream) {
  const float* x    = (const float*)d_in[0];
  const float* Wk   = (const float*)d_in[1];
  const float* Wr   = (const float*)d_in[2];
  const float* bias = (const float*)d_in[3];
  float* out = (float*)d_out;

  // Sentinel-fill the h history (graph-capturable async memset).
  hipMemsetAsync(out, 0xFF, (size_t)out_size * sizeof(float), stream);
  lstm_persistent<<<256, 512, 0, stream>>>(x, Wk, Wr, bias, out);
}